// Round 5
// baseline (4677.438 us; speedup 1.0000x reference)
//
#include <hip/hip_runtime.h>
#include <cstdint>

#define T_STEPS 400
#define B_SZ    256
#define NIN_SZ  64
#define H_SZ    512
#define NOUT_SZ 16
#define NEXC    409            // int(0.8*512)
#define MEMBERS 8              // column-slice members per group
#define BG      4              // batches per group
#define CSL     64             // columns per member
#define NTHR    512
#define NBLK    512            // 64 groups x 8 members, 2 WGs/CU
#define KEXT    576            // 512 recurrent + 64 input rows
#define KR      18             // K rows per thread (576 / 32 kg)
#define TAG_BASE 0x5A5A0000u

#define RED4(a)                                                   \
    a.x += __shfl_xor(a.x, 16); a.y += __shfl_xor(a.y, 16);       \
    a.z += __shfl_xor(a.z, 16); a.w += __shfl_xor(a.w, 16);       \
    a.x += __shfl_xor(a.x, 32); a.y += __shfl_xor(a.y, 32);       \
    a.z += __shfl_xor(a.z, 32); a.w += __shfl_xor(a.w, 32);

// ---------------------------------------------------------------------------
// 512 WGs = 64 batch-groups x 8 column-members (members adjacent in bid so a
// group can never be split across a residency window). W slice in registers
// (72 VGPR). h_post exchanged via value+tag 8-byte relaxed system atomics in
// the (scratch) logits region of d_out: no fences, no cache invalidates, no
// vmcnt drain, no separate flag round-trip.
// ---------------------------------------------------------------------------
__global__ __launch_bounds__(NTHR, 4)
void biornn_main(const float* __restrict__ x,
                 const float* __restrict__ noise,
                 const float* __restrict__ wrnn_raw,
                 const float* __restrict__ win_raw,
                 const float* __restrict__ brnn,
                 uint64_t* __restrict__ hpx,     // [2][B_SZ][H_SZ] tagged hp
                 float* __restrict__ out_h,
                 float* __restrict__ out_sx,
                 float* __restrict__ out_su)
{
    __shared__ __align__(16) float hpT[KEXT * BG];      // [k][b]  9.2 KB
    __shared__ __align__(16) float pbuf[8 * BG * 64];   // [wave][b][cc] 8 KB
    __shared__ float brnn_l[CSL];

    const int tid = threadIdx.x;
    const int bid = blockIdx.x;
    const int m   = bid & 7;           // member (column slice)
    const int g   = bid >> 3;          // batch group
    const int c0  = m * CSL;
    const int b0  = g * BG;

    const int kg  = tid >> 4;          // K-split group 0..31
    const int cg4 = (tid & 15) * 4;    // 4 owned cols within slice
    const int wv  = tid >> 6;          // wave 0..7
    const bool owner = (tid < BG * CSL);   // 256 owner threads: one (b,j) pair
    const int cb  = tid >> 6;          // owner batch 0..3
    const int cc  = tid & 63;          // owner local col

    // ---- one-time: W slice into registers, relu + Dale sign inline ----
    float4 Wv[KR];
#pragma unroll
    for (int i = 0; i < KR; ++i) {
        const int k = kg * KR + i;
        const float* src = (k < H_SZ)
            ? &wrnn_raw[(size_t)k * H_SZ + c0 + cg4]
            : &win_raw[(size_t)(k - H_SZ) * H_SZ + c0 + cg4];
        float4 v = *(const float4*)src;
        const float sgn = (k < H_SZ && k >= NEXC) ? -1.0f : 1.0f;
        Wv[i] = make_float4(fmaxf(v.x, 0.0f) * sgn, fmaxf(v.y, 0.0f) * sgn,
                            fmaxf(v.z, 0.0f) * sgn, fmaxf(v.w, 0.0f) * sgn);
    }
    if (tid < CSL) brnn_l[tid] = brnn[c0 + tid];

    // STP constants: parity of global column (c0 even => parity(tid) works
    // both for hpT row j=tid and for owner column j=c0+cc, cc=tid&63)
    const bool  fac   = ((tid & 1) == 0);
    const float Uj    = fac ? 0.15f : 0.45f;
    const float a_stf = fac ? (10.0f / 1500.0f) : (10.0f / 200.0f);
    const float a_std = fac ? (10.0f / 200.0f)  : (10.0f / 1500.0f);

    // ---- prologue: syn(0) from (h=0.1, sx=1, su=U); hp(0) is uniform ----
    float h = 0.1f, sx, su;
    {
        const float sx0 = 1.0f, su0 = Uj;
        float sxn = sx0 + a_std * (1.0f - sx0) - 0.01f * su0 * sx0 * h;
        float sun = su0 + a_stf * (Uj - su0)   + 0.01f * Uj * (1.0f - su0) * h;
        sx = fminf(fmaxf(sxn, 0.0f), 1.0f);
        su = fminf(fmaxf(sun, 0.0f), 1.0f);
        const float hp0 = su * sx * h;
        ((float4*)hpT)[tid] = make_float4(hp0, hp0, hp0, hp0);  // all 512 rows
        if (owner) {
            const size_t ob = (size_t)(b0 + cb) * H_SZ + c0 + cc;  // t = 0
            out_sx[ob] = sx;
            out_su[ob] = su;
        }
    }
    float xreg = 0.0f;
    if (owner) xreg = x[(size_t)(b0 + cb) * NIN_SZ + cc];   // x(0)

    for (int t = 0; t < T_STEPS; ++t) {
        // stage x(t) into hpT input rows (prefetched last step)
        if (owner) hpT[(H_SZ + cc) * BG + cb] = xreg;
        __syncthreads();                                    // bar0: hpT(t) ready

        float nz = 0.0f;
        if (owner) nz = noise[((size_t)t * B_SZ + b0 + cb) * H_SZ + c0 + cc];

        // ---- phase B: matvec, W in registers, hpT broadcast reads ----
        float4 a0 = make_float4(0.f, 0.f, 0.f, 0.f), a1 = a0, a2 = a0, a3 = a0;
        {
            const float4* hp4 = (const float4*)hpT;
            const int kb = kg * KR;
#pragma unroll
            for (int i = 0; i < KR; ++i) {
                const float4 hv = hp4[kb + i];
                const float4 w  = Wv[i];
                a0.x = fmaf(w.x, hv.x, a0.x); a0.y = fmaf(w.y, hv.x, a0.y);
                a0.z = fmaf(w.z, hv.x, a0.z); a0.w = fmaf(w.w, hv.x, a0.w);
                a1.x = fmaf(w.x, hv.y, a1.x); a1.y = fmaf(w.y, hv.y, a1.y);
                a1.z = fmaf(w.z, hv.y, a1.z); a1.w = fmaf(w.w, hv.y, a1.w);
                a2.x = fmaf(w.x, hv.z, a2.x); a2.y = fmaf(w.y, hv.z, a2.y);
                a2.z = fmaf(w.z, hv.z, a2.z); a2.w = fmaf(w.w, hv.z, a2.w);
                a3.x = fmaf(w.x, hv.w, a3.x); a3.y = fmaf(w.y, hv.w, a3.y);
                a3.z = fmaf(w.z, hv.w, a3.z); a3.w = fmaf(w.w, hv.w, a3.w);
            }
        }
        // prefetch x(t+1) while FMAs retire
        if (owner && t + 1 < T_STEPS)
            xreg = x[((size_t)(t + 1) * B_SZ + b0 + cb) * NIN_SZ + cc];

        // ---- cross-kg reduction inside each wave (4 kg per wave) ----
        RED4(a0) RED4(a1) RED4(a2) RED4(a3)
        if ((tid & 48) == 0) {                 // lanes 0..15 of each wave
            *(float4*)&pbuf[(wv * BG + 0) * 64 + cg4] = a0;
            *(float4*)&pbuf[(wv * BG + 1) * 64 + cg4] = a1;
            *(float4*)&pbuf[(wv * BG + 2) * 64 + cg4] = a2;
            *(float4*)&pbuf[(wv * BG + 3) * 64 + cg4] = a3;
        }
        __syncthreads();                                    // bar1: pbuf ready

        // ---- phase C (owners): combine, membrane, STP(t+1), publish ----
        if (owner) {
            float s = brnn_l[cc];
#pragma unroll
            for (int q = 0; q < 8; ++q)
                s += pbuf[(q * BG + cb) * 64 + cc];
            const float hn = fmaxf(0.9f * h + 0.1f * s + nz, 0.0f);
            out_h[((size_t)t * B_SZ + b0 + cb) * H_SZ + c0 + cc] = hn;
            h = hn;
            if (t + 1 < T_STEPS) {
                float sxn = sx + a_std * (1.0f - sx) - 0.01f * su * sx * hn;
                float sun = su + a_stf * (Uj - su)   + 0.01f * Uj * (1.0f - su) * hn;
                sx = fminf(fmaxf(sxn, 0.0f), 1.0f);
                su = fminf(fmaxf(sun, 0.0f), 1.0f);
                const size_t ob = ((size_t)(t + 1) * B_SZ + b0 + cb) * H_SZ + c0 + cc;
                out_sx[ob] = sx;
                out_su[ob] = su;
                const float hp = su * sx * hn;
                const uint64_t pk =
                    ((uint64_t)(TAG_BASE + (unsigned)(t + 1)) << 32) |
                    (uint64_t)__float_as_uint(hp);
                __hip_atomic_store(
                    &hpx[((size_t)((t + 1) & 1) * B_SZ + b0 + cb) * H_SZ + c0 + cc],
                    pk, __ATOMIC_RELAXED, __HIP_MEMORY_SCOPE_SYSTEM);
            }
        }
        if (t + 1 >= T_STEPS) break;

        // ---- gather hp(t+1): spin on tagged values (no flags, no fences) ----
        {
            const unsigned want = TAG_BASE + (unsigned)(t + 1);
            uint64_t* slot = hpx + ((size_t)((t + 1) & 1) * B_SZ + b0) * H_SZ + tid;
            unsigned done = 0;
            float g0 = 0.f, g1 = 0.f, g2 = 0.f, g3 = 0.f;
            while (__all(done == 15u) == 0) {
                uint64_t v;
                if (!(done & 1u)) {
                    v = __hip_atomic_load(slot, __ATOMIC_RELAXED,
                                          __HIP_MEMORY_SCOPE_SYSTEM);
                    if ((unsigned)(v >> 32) == want) {
                        g0 = __uint_as_float((unsigned)v); done |= 1u;
                    }
                }
                if (!(done & 2u)) {
                    v = __hip_atomic_load(slot + H_SZ, __ATOMIC_RELAXED,
                                          __HIP_MEMORY_SCOPE_SYSTEM);
                    if ((unsigned)(v >> 32) == want) {
                        g1 = __uint_as_float((unsigned)v); done |= 2u;
                    }
                }
                if (!(done & 4u)) {
                    v = __hip_atomic_load(slot + 2 * H_SZ, __ATOMIC_RELAXED,
                                          __HIP_MEMORY_SCOPE_SYSTEM);
                    if ((unsigned)(v >> 32) == want) {
                        g2 = __uint_as_float((unsigned)v); done |= 4u;
                    }
                }
                if (!(done & 8u)) {
                    v = __hip_atomic_load(slot + 3 * H_SZ, __ATOMIC_RELAXED,
                                          __HIP_MEMORY_SCOPE_SYSTEM);
                    if ((unsigned)(v >> 32) == want) {
                        g3 = __uint_as_float((unsigned)v); done |= 8u;
                    }
                }
                if (__all(done == 15u) == 0) __builtin_amdgcn_s_sleep(1);
            }
            ((float4*)hpT)[tid] = make_float4(g0, g1, g2, g3);
        }
        // next bar0 separates gather/x writes from phase-B reads
    }
}

// ---------------------------------------------------------------------------
// logits[t,b,:] = h[t,b,:] @ relu(W_out) + bout  (overwrites the hpx scratch)
// ---------------------------------------------------------------------------
__global__ __launch_bounds__(256)
void logits_k(const float* __restrict__ h, const float* __restrict__ wout_raw,
              const float* __restrict__ bout, float* __restrict__ out) {
    __shared__ float wl[H_SZ * 17];    // padded stride 17
    __shared__ float bl[NOUT_SZ];
    const int tid = threadIdx.x;
    for (int i = tid; i < H_SZ * NOUT_SZ; i += 256)
        wl[(i >> 4) * 17 + (i & 15)] = fmaxf(wout_raw[i], 0.0f);
    if (tid < NOUT_SZ) bl[tid] = bout[tid];
    __syncthreads();
    const size_t row = (size_t)blockIdx.x * 16 + (tid >> 4);
    const int o = tid & 15;
    const float* hr = h + row * H_SZ;
    float s = bl[o];
#pragma unroll 8
    for (int jj = 0; jj < H_SZ; ++jj)
        s = fmaf(hr[jj], wl[jj * 17 + o], s);
    out[row * NOUT_SZ + o] = s;
}

extern "C" void kernel_launch(void* const* d_in, const int* in_sizes, int n_in,
                              void* d_out, int out_size, void* d_ws, size_t ws_size,
                              hipStream_t stream) {
    const float* x     = (const float*)d_in[0];
    const float* noise = (const float*)d_in[1];
    const float* W_in  = (const float*)d_in[2];
    const float* W_rnn = (const float*)d_in[3];
    const float* b_rnn = (const float*)d_in[4];
    const float* W_out = (const float*)d_in[5];
    const float* b_out = (const float*)d_in[6];

    float* out_logits = (float*)d_out;
    float* out_h  = out_logits + (size_t)T_STEPS * B_SZ * NOUT_SZ;
    float* out_sx = out_h  + (size_t)T_STEPS * B_SZ * H_SZ;
    float* out_su = out_sx + (size_t)T_STEPS * B_SZ * H_SZ;

    // hp exchange scratch: first 2 MB of the logits region (6.55 MB);
    // logits_k fully overwrites it afterwards.
    uint64_t* hpx = (uint64_t*)out_logits;

    biornn_main<<<NBLK, NTHR, 0, stream>>>(x, noise, W_rnn, W_in, b_rnn,
                                           hpx, out_h, out_sx, out_su);
    logits_k<<<(T_STEPS * B_SZ) / 16, 256, 0, stream>>>(
        out_h, W_out, b_out, out_logits);
}

// Round 6
// 2408.920 us; speedup vs baseline: 1.9417x; 1.9417x over previous
//
#include <hip/hip_runtime.h>
#include <cstdint>

#define T_STEPS 400
#define B_SZ    256
#define NIN_SZ  64
#define H_SZ    512
#define NOUT_SZ 16
#define NEXC    409            // int(0.8*512)
#define MEMBERS 8              // column-slice members per group
#define BG      4              // batches per group
#define CSL     64             // columns per member
#define NTHR    512
#define NBLK    512            // 64 groups x 8 members
#define KEXT    576            // 512 recurrent + 64 input rows
#define KR      18             // K rows per thread (576 / 32 kg)
#define TAG_BASE 0x5A5A0000u

#define RED4(a)                                                   \
    a.x += __shfl_xor(a.x, 16); a.y += __shfl_xor(a.y, 16);       \
    a.z += __shfl_xor(a.z, 16); a.w += __shfl_xor(a.w, 16);       \
    a.x += __shfl_xor(a.x, 32); a.y += __shfl_xor(a.y, 32);       \
    a.z += __shfl_xor(a.z, 32); a.w += __shfl_xor(a.w, 32);

// ---------------------------------------------------------------------------
// 512 WGs = 64 batch-groups x 8 column-members (members adjacent in bid, so
// whole groups become resident together; groups are mutually independent).
// W slice in registers (72 VGPR, asm-pinned against rematerialization).
// h_post exchanged as (tag<<32)|value 8-byte packets through sc0/sc1
// global ops: Infinity-Cache coherent AND cached — no HBM polling, no
// fences, no cache-invalidates, no vmcnt drains, no flag round-trip.
// Exchange buffer lives in the logits region of d_out (overwritten by
// logits_k afterwards). Poison 0xAAAAAAAA / memset-0 never match a tag;
// cross-replay leftovers never match the wanted tag within a launch.
// ---------------------------------------------------------------------------
__global__ __launch_bounds__(NTHR, 2)
void biornn_main(const float* __restrict__ x,
                 const float* __restrict__ noise,
                 const float* __restrict__ wrnn_raw,
                 const float* __restrict__ win_raw,
                 const float* __restrict__ brnn,
                 uint64_t* __restrict__ hpx,     // [2][B_SZ][H_SZ] tagged hp
                 float* __restrict__ out_h,
                 float* __restrict__ out_sx,
                 float* __restrict__ out_su)
{
    __shared__ __align__(16) float hpT[KEXT * BG];      // [k][b]  9.2 KB
    __shared__ __align__(16) float pbuf[8 * BG * 64];   // [wave][b][cc] 8 KB
    __shared__ float brnn_l[CSL];

    const int tid = threadIdx.x;
    const int bid = blockIdx.x;
    const int m   = bid & 7;           // member (column slice)
    const int g   = bid >> 3;          // batch group
    const int c0  = m * CSL;
    const int b0  = g * BG;

    const int kg  = tid >> 4;          // K-split group 0..31
    const int cg4 = (tid & 15) * 4;    // 4 owned cols within slice
    const int wv  = tid >> 6;          // wave 0..7
    const bool owner = (tid < BG * CSL);   // 256 owners: one (batch,col) pair
    const int cb  = tid >> 6;          // owner batch 0..3
    const int cc  = tid & 63;          // owner local col

    // ---- one-time: W slice into registers, relu + Dale sign inline ----
    float4 Wv[KR];
#pragma unroll
    for (int i = 0; i < KR; ++i) {
        const int k = kg * KR + i;
        const float* src = (k < H_SZ)
            ? &wrnn_raw[(size_t)k * H_SZ + c0 + cg4]
            : &win_raw[(size_t)(k - H_SZ) * H_SZ + c0 + cg4];
        float4 v = *(const float4*)src;
        const float sgn = (k < H_SZ && k >= NEXC) ? -1.0f : 1.0f;
        Wv[i] = make_float4(fmaxf(v.x, 0.0f) * sgn, fmaxf(v.y, 0.0f) * sgn,
                            fmaxf(v.z, 0.0f) * sgn, fmaxf(v.w, 0.0f) * sgn);
    }
    // pin: make Wv asm-defined so the compiler cannot rematerialize the
    // loads inside the time loop (R4 failure mode: VGPR=64, W re-streamed)
#pragma unroll
    for (int i = 0; i < KR; ++i)
        asm volatile("" : "+v"(Wv[i].x), "+v"(Wv[i].y),
                          "+v"(Wv[i].z), "+v"(Wv[i].w));

    if (tid < CSL) brnn_l[tid] = brnn[c0 + tid];

    // STP constants by column parity (c0 is a multiple of 64 -> parity(tid)
    // equals parity of the global column for both tid-as-j and c0+cc)
    const bool  fac   = ((tid & 1) == 0);
    const float Uj    = fac ? 0.15f : 0.45f;
    const float a_stf = fac ? (10.0f / 1500.0f) : (10.0f / 200.0f);
    const float a_std = fac ? (10.0f / 200.0f)  : (10.0f / 1500.0f);

    // ---- prologue: syn(0) from (h=0.1, sx=1, su=U); hp(0) uniform ----
    float h = 0.1f, sx, su;
    {
        const float sx0 = 1.0f, su0 = Uj;
        float sxn = sx0 + a_std * (1.0f - sx0) - 0.01f * su0 * sx0 * h;
        float sun = su0 + a_stf * (Uj - su0)   + 0.01f * Uj * (1.0f - su0) * h;
        sx = fminf(fmaxf(sxn, 0.0f), 1.0f);
        su = fminf(fmaxf(sun, 0.0f), 1.0f);
        const float hp0 = su * sx * h;
        ((float4*)hpT)[tid] = make_float4(hp0, hp0, hp0, hp0);
        if (owner) {
            const size_t ob = (size_t)(b0 + cb) * H_SZ + c0 + cc;  // t = 0
            out_sx[ob] = sx;
            out_su[ob] = su;
        }
    }
    float xreg = 0.0f;
    if (owner) xreg = x[(size_t)(b0 + cb) * NIN_SZ + cc];   // x(0)

    for (int t = 0; t < T_STEPS; ++t) {
        // stage x(t) into hpT input rows (prefetched previous step)
        if (owner) hpT[(H_SZ + cc) * BG + cb] = xreg;
        __syncthreads();                                    // bar0: hpT(t) ready

        float nz = 0.0f;
        if (owner) nz = noise[((size_t)t * B_SZ + b0 + cb) * H_SZ + c0 + cc];

        // ---- phase B: matvec, W in registers, hpT broadcast reads ----
        float4 a0 = make_float4(0.f, 0.f, 0.f, 0.f), a1 = a0, a2 = a0, a3 = a0;
        {
            const float4* hp4 = (const float4*)hpT;
            const int kb = kg * KR;
#pragma unroll
            for (int i = 0; i < KR; ++i) {
                const float4 hv = hp4[kb + i];
                const float4 w  = Wv[i];
                a0.x = fmaf(w.x, hv.x, a0.x); a0.y = fmaf(w.y, hv.x, a0.y);
                a0.z = fmaf(w.z, hv.x, a0.z); a0.w = fmaf(w.w, hv.x, a0.w);
                a1.x = fmaf(w.x, hv.y, a1.x); a1.y = fmaf(w.y, hv.y, a1.y);
                a1.z = fmaf(w.z, hv.y, a1.z); a1.w = fmaf(w.w, hv.y, a1.w);
                a2.x = fmaf(w.x, hv.z, a2.x); a2.y = fmaf(w.y, hv.z, a2.y);
                a2.z = fmaf(w.z, hv.z, a2.z); a2.w = fmaf(w.w, hv.z, a2.w);
                a3.x = fmaf(w.x, hv.w, a3.x); a3.y = fmaf(w.y, hv.w, a3.y);
                a3.z = fmaf(w.z, hv.w, a3.z); a3.w = fmaf(w.w, hv.w, a3.w);
            }
        }
        // prefetch x(t+1) while FMAs retire
        if (owner && t + 1 < T_STEPS)
            xreg = x[((size_t)(t + 1) * B_SZ + b0 + cb) * NIN_SZ + cc];

        // ---- cross-kg reduction inside each wave (4 kg per wave) ----
        RED4(a0) RED4(a1) RED4(a2) RED4(a3)
        if ((tid & 48) == 0) {                 // lanes 0..15 of each wave
            *(float4*)&pbuf[(wv * BG + 0) * 64 + cg4] = a0;
            *(float4*)&pbuf[(wv * BG + 1) * 64 + cg4] = a1;
            *(float4*)&pbuf[(wv * BG + 2) * 64 + cg4] = a2;
            *(float4*)&pbuf[(wv * BG + 3) * 64 + cg4] = a3;
        }
        __syncthreads();                                    // bar1: pbuf ready

        // ---- phase C (owners): combine, membrane, STP(t+1), publish ----
        if (owner) {
            float s = brnn_l[cc];
#pragma unroll
            for (int q = 0; q < 8; ++q)
                s += pbuf[(q * BG + cb) * 64 + cc];
            const float hn = fmaxf(0.9f * h + 0.1f * s + nz, 0.0f);
            out_h[((size_t)t * B_SZ + b0 + cb) * H_SZ + c0 + cc] = hn;
            h = hn;
            if (t + 1 < T_STEPS) {
                float sxn = sx + a_std * (1.0f - sx) - 0.01f * su * sx * hn;
                float sun = su + a_stf * (Uj - su)   + 0.01f * Uj * (1.0f - su) * hn;
                sx = fminf(fmaxf(sxn, 0.0f), 1.0f);
                su = fminf(fmaxf(sun, 0.0f), 1.0f);
                const size_t ob = ((size_t)(t + 1) * B_SZ + b0 + cb) * H_SZ + c0 + cc;
                out_sx[ob] = sx;
                out_su[ob] = su;
                const float hp = su * sx * hn;
                const uint64_t pk =
                    ((uint64_t)(TAG_BASE + (unsigned)(t + 1)) << 32) |
                    (uint64_t)__float_as_uint(hp);
                uint64_t* sp = hpx +
                    ((size_t)((t + 1) & 1) * B_SZ + b0 + cb) * H_SZ + c0 + cc;
                asm volatile("global_store_dwordx2 %0, %1, off sc0 sc1"
                             :: "v"(sp), "v"(pk) : "memory");
            }
        }
        if (t + 1 >= T_STEPS) break;

        // ---- gather hp(t+1): batched tagged poll through the IC ----
        {
            const unsigned want = TAG_BASE + (unsigned)(t + 1);
            uint64_t* p0 = hpx + ((size_t)((t + 1) & 1) * B_SZ + b0) * H_SZ + tid;
            uint64_t* p1 = p0 + H_SZ;
            uint64_t* p2 = p0 + 2 * H_SZ;
            uint64_t* p3 = p0 + 3 * H_SZ;
            uint64_t v0, v1, v2, v3;
            while (true) {
                asm volatile(
                    "global_load_dwordx2 %0, %4, off sc0 sc1\n\t"
                    "global_load_dwordx2 %1, %5, off sc0 sc1\n\t"
                    "global_load_dwordx2 %2, %6, off sc0 sc1\n\t"
                    "global_load_dwordx2 %3, %7, off sc0 sc1\n\t"
                    "s_waitcnt vmcnt(0)"
                    : "=&v"(v0), "=&v"(v1), "=&v"(v2), "=&v"(v3)
                    : "v"(p0), "v"(p1), "v"(p2), "v"(p3)
                    : "memory");
                const bool ok = ((unsigned)(v0 >> 32) == want) &
                                ((unsigned)(v1 >> 32) == want) &
                                ((unsigned)(v2 >> 32) == want) &
                                ((unsigned)(v3 >> 32) == want);
                if (__all(ok)) break;
                __builtin_amdgcn_s_sleep(1);
            }
            ((float4*)hpT)[tid] =
                make_float4(__uint_as_float((unsigned)v0),
                            __uint_as_float((unsigned)v1),
                            __uint_as_float((unsigned)v2),
                            __uint_as_float((unsigned)v3));
        }
        // next bar0 separates gather/x writes from phase-B reads
    }
}

// ---------------------------------------------------------------------------
// logits[t,b,:] = h[t,b,:] @ relu(W_out) + bout  (overwrites the hpx scratch)
// ---------------------------------------------------------------------------
__global__ __launch_bounds__(256)
void logits_k(const float* __restrict__ h, const float* __restrict__ wout_raw,
              const float* __restrict__ bout, float* __restrict__ out) {
    __shared__ float wl[H_SZ * 17];    // padded stride 17
    __shared__ float bl[NOUT_SZ];
    const int tid = threadIdx.x;
    for (int i = tid; i < H_SZ * NOUT_SZ; i += 256)
        wl[(i >> 4) * 17 + (i & 15)] = fmaxf(wout_raw[i], 0.0f);
    if (tid < NOUT_SZ) bl[tid] = bout[tid];
    __syncthreads();
    const size_t row = (size_t)blockIdx.x * 16 + (tid >> 4);
    const int o = tid & 15;
    const float* hr = h + row * H_SZ;
    float s = bl[o];
#pragma unroll 8
    for (int jj = 0; jj < H_SZ; ++jj)
        s = fmaf(hr[jj], wl[jj * 17 + o], s);
    out[row * NOUT_SZ + o] = s;
}

extern "C" void kernel_launch(void* const* d_in, const int* in_sizes, int n_in,
                              void* d_out, int out_size, void* d_ws, size_t ws_size,
                              hipStream_t stream) {
    const float* x     = (const float*)d_in[0];
    const float* noise = (const float*)d_in[1];
    const float* W_in  = (const float*)d_in[2];
    const float* W_rnn = (const float*)d_in[3];
    const float* b_rnn = (const float*)d_in[4];
    const float* W_out = (const float*)d_in[5];
    const float* b_out = (const float*)d_in[6];

    float* out_logits = (float*)d_out;
    float* out_h  = out_logits + (size_t)T_STEPS * B_SZ * NOUT_SZ;
    float* out_sx = out_h  + (size_t)T_STEPS * B_SZ * H_SZ;
    float* out_su = out_sx + (size_t)T_STEPS * B_SZ * H_SZ;

    // hp exchange scratch: first 2 MB of the logits region (6.55 MB);
    // logits_k fully overwrites it afterwards.
    uint64_t* hpx = (uint64_t*)out_logits;

    biornn_main<<<NBLK, NTHR, 0, stream>>>(x, noise, W_rnn, W_in, b_rnn,
                                           hpx, out_h, out_sx, out_su);
    logits_k<<<(T_STEPS * B_SZ) / 16, 256, 0, stream>>>(
        out_h, W_out, b_out, out_logits);
}